// Round 1
// baseline (14.911 us; speedup 1.0000x reference)
//
#include <hip/hip_runtime.h>

// PointQuantizer: nearest-cell-center quantization on a regular 32^3 grid.
// enc = i*1024 + j*32 + l, i = clamp(floor((x+1)*16), 0, 31)  (exact
// equivalent of the reference's argmin over 32768 grid centers, since the
// grid is separable). Then per-row sort of enc (bitonic, LDS) and voxel
// occupancy output in {-0.8, 0.8}.

#define VW 32          // voxel grid resolution
#define VK (VW*VW*VW)  // 32768 voxels
#define NPTS 1024      // points per batch row
#define NB 4           // batch

__global__ __launch_bounds__(NPTS) void pq_kernel(const float* __restrict__ x,
                                                  float* __restrict__ out) {
    const int b = blockIdx.x;
    const int t = threadIdx.x;

    float* enc_out = out;                    // (NB, NPTS) as float32
    float* vox_out = out + NB * NPTS;        // (NB, VK)   as float32

    __shared__ int s[NPTS];

    // --- compute cell index for this thread's point ---
    const float* p = x + (size_t)(b * NPTS + t) * 3;
    float px = p[0], py = p[1], pz = p[2];
    int i = (int)floorf((px + 1.0f) * 16.0f);
    int j = (int)floorf((py + 1.0f) * 16.0f);
    int l = (int)floorf((pz + 1.0f) * 16.0f);
    i = min(max(i, 0), VW - 1);
    j = min(max(j, 0), VW - 1);
    l = min(max(l, 0), VW - 1);
    int enc = i * (VW * VW) + j * VW + l;
    s[t] = enc;

    // --- init this batch's voxel slab to -0.8, then scatter 0.8 ---
    float* vb = vox_out + (size_t)b * VK;
    #pragma unroll
    for (int r = 0; r < VK / NPTS; ++r)
        vb[r * NPTS + t] = -0.8f;
    __syncthreads();              // also publishes s[] for the sort
    vb[enc] = 0.8f;               // same-value races are benign

    // --- bitonic sort of s[0..1023] ascending ---
    for (int k = 2; k <= NPTS; k <<= 1) {
        for (int jj = k >> 1; jj > 0; jj >>= 1) {
            int ixj = t ^ jj;
            if (ixj > t) {
                int a = s[t], c = s[ixj];
                bool up = ((t & k) == 0);
                if ((a > c) == up) { s[t] = c; s[ixj] = a; }
            }
            __syncthreads();
        }
    }

    enc_out[b * NPTS + t] = (float)s[t];
}

extern "C" void kernel_launch(void* const* d_in, const int* in_sizes, int n_in,
                              void* d_out, int out_size, void* d_ws, size_t ws_size,
                              hipStream_t stream) {
    const float* x = (const float*)d_in[0];   // (4, 1024, 3) f32
    // d_in[1] = grid_points (32768, 3) f32 — not needed (regular grid)
    float* out = (float*)d_out;               // enc (4,1024) ++ voxel (4,32768)

    pq_kernel<<<NB, NPTS, 0, stream>>>(x, out);
}

// Round 2
// 12.085 us; speedup vs baseline: 1.2339x; 1.2339x over previous
//
#include <hip/hip_runtime.h>

// PointQuantizer: nearest-cell-center quantization on a regular 32^3 grid.
// enc = i*1024 + j*32 + l, i = clamp(floor((x+1)*16), 0, 31)  — exact
// equivalent of the reference argmin over the 32768 regular grid centers.
// Per-row ascending sort of enc via hybrid bitonic:
//   - jj <= 32 stages in registers via __shfl_xor (wave=64), no barriers
//   - jj >= 64 stages via ping-pong LDS, 1 barrier each (10 total)
// Voxel output in {-0.8, 0.8}; the -0.8 fill is issued first and drains
// under the register sort; the first __syncthreads (vmcnt drain) orders
// the 0.8 scatter after the fill.

#define VW 32          // voxel grid resolution
#define VK (VW*VW*VW)  // 32768 voxels
#define NPTS 1024      // points per batch row
#define NB 4           // batch

__device__ __forceinline__ int cmpex_shfl(int v, int jj, int k, int t) {
    int pv = __shfl_xor(v, jj);
    bool keepmin = (((t & jj) == 0) == ((t & k) == 0));
    return keepmin ? min(v, pv) : max(v, pv);
}

__global__ __launch_bounds__(NPTS) void pq_kernel(const float* __restrict__ x,
                                                  float* __restrict__ out) {
    const int b = blockIdx.x;
    const int t = threadIdx.x;

    float* enc_out = out;                                  // (NB, NPTS) f32
    float* vox = out + NB * NPTS + (size_t)b * VK;         // this row's (VK)

    __shared__ int sb[2][NPTS];                            // ping-pong, 8 KiB

    // --- cell index (separable nearest-center on regular grid) ---
    const float* p = x + (size_t)(b * NPTS + t) * 3;
    float px = p[0], py = p[1], pz = p[2];
    int i = min(max((int)floorf((px + 1.0f) * 16.0f), 0), VW - 1);
    int j = min(max((int)floorf((py + 1.0f) * 16.0f), 0), VW - 1);
    int l = min(max((int)floorf((pz + 1.0f) * 16.0f), 0), VW - 1);
    const int enc = i * (VW * VW) + j * VW + l;
    int v = enc;

    // --- issue -0.8 fill now; stores drain under the register sort ---
    const float4 neg = make_float4(-0.8f, -0.8f, -0.8f, -0.8f);
    float4* v4 = (float4*)vox;
    #pragma unroll
    for (int r = 0; r < VK / 4 / NPTS; ++r)   // 8 x float4 per thread
        v4[r * NPTS + t] = neg;

    // --- intra-wave bitonic, k = 2..64 (21 stages, zero barriers) ---
    #pragma unroll
    for (int k = 2; k <= 64; k <<= 1)
        #pragma unroll
        for (int jj = k >> 1; jj > 0; jj >>= 1)
            v = cmpex_shfl(v, jj, k, t);

    int cur = 0;
    sb[0][t] = v;
    __syncthreads();          // publishes sb AND drains the fill stores
    vox[enc] = 0.8f;          // scatter after fill; same-value races benign

    // --- cross-wave merges, k = 128..1024 ---
    #pragma unroll
    for (int k = 128; k <= NPTS; k <<= 1) {
        for (int jj = k >> 1; jj >= 64; jj >>= 1) {        // cross-wave stage
            int pv = sb[cur][t ^ jj];
            bool keepmin = (((t & jj) == 0) == ((t & k) == 0));
            v = keepmin ? min(v, pv) : max(v, pv);
            sb[cur ^ 1][t] = v;
            __syncthreads();
            cur ^= 1;
        }
        #pragma unroll
        for (int jj = 32; jj > 0; jj >>= 1)                // in-register tail
            v = cmpex_shfl(v, jj, k, t);
        if (k < NPTS) {                                    // publish for next k
            sb[cur ^ 1][t] = v;
            __syncthreads();
            cur ^= 1;
        }
    }

    enc_out[b * NPTS + t] = (float)v;
}

extern "C" void kernel_launch(void* const* d_in, const int* in_sizes, int n_in,
                              void* d_out, int out_size, void* d_ws, size_t ws_size,
                              hipStream_t stream) {
    const float* x = (const float*)d_in[0];   // (4, 1024, 3) f32
    // d_in[1] = grid_points (32768, 3) f32 — not needed (regular grid)
    float* out = (float*)d_out;               // enc (4,1024) ++ voxel (4,32768)

    pq_kernel<<<NB, NPTS, 0, stream>>>(x, out);
}

// Round 3
// 10.783 us; speedup vs baseline: 1.3829x; 1.1208x over previous
//
#include <hip/hip_runtime.h>

// PointQuantizer: nearest-cell-center quantization on a regular 32^3 grid.
// enc = i*1024 + j*32 + l, i = clamp(floor((x+1)*16), 0, 31)  — exact
// equivalent of the reference argmin over the 32768 regular grid centers.
//
// Structure (1 block per batch row, 1024 threads):
//   1. LDS occupancy bitmap (1024 words) via ds_or atomics — each voxel is
//      then written EXACTLY ONCE with its final value (+-0.8), coalesced
//      float4 stores. No fill->scatter ordering dependency.
//   2. Hybrid bitonic sort of enc: jj<=32 stages in registers (__shfl_xor,
//      wave=64), jj>=64 stages via ping-pong LDS with RAW s_barrier +
//      lgkmcnt(0)-only waits — never vmcnt(0) — so the 128 KB/block of
//      voxel stores issued in step 1 drain under the whole sort chain
//      instead of stalling the first barrier (__syncthreads would drain
//      vmcnt(0) per wave per barrier).

#define VW 32          // voxel grid resolution
#define VK (VW*VW*VW)  // 32768 voxels
#define NPTS 1024      // points per batch row
#define NB 4           // batch
#define NWORDS (VK/32) // 1024 bitmap words

// Barrier with LDS-only drain; "memory" clobber fences compiler reordering
// of all memory ops across it (stores stay issued, ds ops stay ordered).
#define BARRIER_LDS() asm volatile("s_waitcnt lgkmcnt(0)\n\ts_barrier" ::: "memory")

__device__ __forceinline__ int cmpex_shfl(int v, int jj, int k, int t) {
    int pv = __shfl_xor(v, jj);
    bool keepmin = (((t & jj) == 0) == ((t & k) == 0));
    return keepmin ? min(v, pv) : max(v, pv);
}

__global__ __launch_bounds__(NPTS) void pq_kernel(const float* __restrict__ x,
                                                  float* __restrict__ out) {
    const int b = blockIdx.x;
    const int t = threadIdx.x;

    float* enc_out = out;                              // (NB, NPTS) f32
    float* vox = out + NB * NPTS + (size_t)b * VK;     // this row's (VK)

    __shared__ unsigned bm[NWORDS];                    // 4 KiB bitmap
    __shared__ int sb[2][NPTS];                        // 8 KiB ping-pong

    bm[t] = 0u;

    // --- cell index (separable nearest-center on regular grid) ---
    const float* p = x + (size_t)(b * NPTS + t) * 3;
    float px = p[0], py = p[1], pz = p[2];
    int i = min(max((int)floorf((px + 1.0f) * 16.0f), 0), VW - 1);
    int j = min(max((int)floorf((py + 1.0f) * 16.0f), 0), VW - 1);
    int l = min(max((int)floorf((pz + 1.0f) * 16.0f), 0), VW - 1);
    int v = i * (VW * VW) + j * VW + l;

    BARRIER_LDS();                         // bm zeroed
    atomicOr(&bm[v >> 5], 1u << (v & 31)); // ds_or, lgkm-counted
    BARRIER_LDS();                         // bitmap complete

    // --- expand bitmap -> voxel outputs; each voxel written once, final
    //     value; coalesced 1 KiB/wave-instr float4 stores. Issued NOW so
    //     they drain under the sort below. ---
    float4* v4 = (float4*)vox;
    #pragma unroll
    for (int g = 0; g < 8; ++g) {
        int m = g * NPTS + t;              // float4 index: voxels 4m..4m+3
        unsigned nib = bm[m >> 3] >> ((m & 7) * 4);  // 8 lanes share a word
        float4 f;
        f.x = (nib & 1u) ? 0.8f : -0.8f;
        f.y = (nib & 2u) ? 0.8f : -0.8f;
        f.z = (nib & 4u) ? 0.8f : -0.8f;
        f.w = (nib & 8u) ? 0.8f : -0.8f;
        v4[m] = f;
    }

    // --- intra-wave bitonic, k = 2..64 (21 stages, zero barriers) ---
    #pragma unroll
    for (int k = 2; k <= 64; k <<= 1)
        #pragma unroll
        for (int jj = k >> 1; jj > 0; jj >>= 1)
            v = cmpex_shfl(v, jj, k, t);

    int cur = 0;
    sb[0][t] = v;
    BARRIER_LDS();

    // --- cross-wave merges, k = 128..1024 (lgkm-only barriers) ---
    #pragma unroll
    for (int k = 128; k <= NPTS; k <<= 1) {
        for (int jj = k >> 1; jj >= 64; jj >>= 1) {    // cross-wave stage
            int pv = sb[cur][t ^ jj];
            bool keepmin = (((t & jj) == 0) == ((t & k) == 0));
            v = keepmin ? min(v, pv) : max(v, pv);
            sb[cur ^ 1][t] = v;
            BARRIER_LDS();
            cur ^= 1;
        }
        #pragma unroll
        for (int jj = 32; jj > 0; jj >>= 1)            // in-register tail
            v = cmpex_shfl(v, jj, k, t);
        if (k < NPTS) {                                // publish for next k
            sb[cur ^ 1][t] = v;
            BARRIER_LDS();
            cur ^= 1;
        }
    }

    enc_out[b * NPTS + t] = (float)v;
}

extern "C" void kernel_launch(void* const* d_in, const int* in_sizes, int n_in,
                              void* d_out, int out_size, void* d_ws, size_t ws_size,
                              hipStream_t stream) {
    const float* x = (const float*)d_in[0];   // (4, 1024, 3) f32
    // d_in[1] = grid_points (32768, 3) f32 — not needed (regular grid)
    float* out = (float*)d_out;               // enc (4,1024) ++ voxel (4,32768)

    pq_kernel<<<NB, NPTS, 0, stream>>>(x, out);
}